// Round 1
// baseline (2207.866 us; speedup 1.0000x reference)
//
#include <hip/hip_runtime.h>
#include <math.h>

#define SS 2048
#define NN 1024
#define DD 1024
#define HH 16
#define HDIM 64
#define CONDD 128

__device__ __forceinline__ float gelu_tanh(float x) {
    float x3 = x * x * x;
    return 0.5f * x * (1.0f + tanhf(0.79788456080286535588f * (x + 0.044715f * x3)));
}

// mods[6D] = adaLN_b + adaLN_w @ c      (W: [6D, COND] row-major)
__global__ void k_adaln(const float* __restrict__ c, const float* __restrict__ w,
                        const float* __restrict__ b, float* __restrict__ mods) {
    int o = blockIdx.x * 256 + threadIdx.x;
    float s = b[o];
    const float* wr = w + (size_t)o * CONDD;
    for (int k = 0; k < CONDD; ++k) s += c[k] * wr[k];
    mods[o] = s;
}

// out[row] = LN(x[row]) * w * (1 + mods[sc_idx*D + :]) + mods[sh_idx*D + :]
__global__ void k_ln_mod(const float* __restrict__ x, const float* __restrict__ w,
                         const float* __restrict__ mods, int sh_idx, int sc_idx,
                         float* __restrict__ out) {
    int row = blockIdx.x;
    int tid = threadIdx.x;
    const float* xr = x + (size_t)row * DD;
    float lx[4];
    float s = 0.f, s2 = 0.f;
    for (int i = 0; i < 4; ++i) {
        float v = xr[tid + i * 256];
        lx[i] = v; s += v; s2 += v * v;
    }
    __shared__ float rs[256], rs2[256];
    rs[tid] = s; rs2[tid] = s2; __syncthreads();
    for (int off = 128; off > 0; off >>= 1) {
        if (tid < off) { rs[tid] += rs[tid + off]; rs2[tid] += rs2[tid + off]; }
        __syncthreads();
    }
    float mu = rs[0] * (1.0f / DD);
    float var = rs2[0] * (1.0f / DD) - mu * mu;
    float rstd = rsqrtf(var + 1e-5f);
    const float* sh = mods + sh_idx * DD;
    const float* sc = mods + sc_idx * DD;
    float* orow = out + (size_t)row * DD;
    for (int i = 0; i < 4; ++i) {
        int d = tid + i * 256;
        orow[d] = (lx[i] - mu) * rstd * w[d] * (1.0f + sc[d]) + sh[d];
    }
}

// C[M, Nout] = A[M, K] @ W[Nout, K]^T  with fused epilogues
// MODE 0: C = acc
// MODE 1: C = gate[n]*acc + resid          (attn out proj)
// MODE 2: C = gelu(acc + bias[n])          (mlp1)
// MODE 3: C = gate[n]*(acc + bias[n]) + resid   (mlp2 -> final out)
template <int MODE>
__global__ void k_gemm(const float* __restrict__ A, const float* __restrict__ W,
                       const float* __restrict__ bias, const float* __restrict__ gate,
                       const float* __restrict__ resid, float* __restrict__ C,
                       int M, int Nout, int K) {
    __shared__ __align__(16) float As[16][68];
    __shared__ __align__(16) float Ws[16][68];
    int tid = threadIdx.x;
    int tx = tid & 15, ty = tid >> 4;
    int n0 = blockIdx.x * 64, m0 = blockIdx.y * 64;
    float acc[4][4] = {};
    for (int k0 = 0; k0 < K; k0 += 16) {
        for (int i = 0; i < 4; ++i) {
            int idx = tid + i * 256;
            int r = idx >> 4, kk = idx & 15;
            As[kk][r] = A[(size_t)(m0 + r) * K + k0 + kk];
            Ws[kk][r] = W[(size_t)(n0 + r) * K + k0 + kk];
        }
        __syncthreads();
#pragma unroll
        for (int kk = 0; kk < 16; ++kk) {
            float4 a = *(const float4*)&As[kk][ty * 4];
            float4 b = *(const float4*)&Ws[kk][tx * 4];
            float av[4] = {a.x, a.y, a.z, a.w};
            float bv[4] = {b.x, b.y, b.z, b.w};
#pragma unroll
            for (int i = 0; i < 4; ++i)
#pragma unroll
                for (int j = 0; j < 4; ++j) acc[i][j] += av[i] * bv[j];
        }
        __syncthreads();
    }
    for (int i = 0; i < 4; ++i) {
        int m = m0 + ty * 4 + i;
        float outv[4];
        for (int j = 0; j < 4; ++j) {
            int n = n0 + tx * 4 + j;
            float v = acc[i][j];
            if (MODE == 1) v = gate[n] * v + resid[(size_t)m * Nout + n];
            if (MODE == 2) v = gelu_tanh(v + bias[n]);
            if (MODE == 3) v = gate[n] * (v + bias[n]) + resid[(size_t)m * Nout + n];
            outv[j] = v;
        }
        *(float4*)&C[(size_t)m * Nout + n0 + tx * 4] = *(float4*)outv;
    }
}

// in-place RoPE on qkv [S, 3, H, HD]; applied to q, k AND v; pos = s mod N
__global__ void k_rope(float* __restrict__ qkv, const float* __restrict__ cosT,
                       const float* __restrict__ sinT) {
    int s = blockIdx.x;
    int pos = s & (NN - 1);
    float* row = qkv + (size_t)s * 3 * DD;
    for (int p = threadIdx.x; p < 3 * HH * 32; p += 256) {
        int j = p & 31;
        int head = p >> 5;          // 0..47 covers [3][H]
        int base = head * HDIM;
        float cv = cosT[pos * 32 + j];
        float sv = sinT[pos * 32 + j];
        float x1 = row[base + j];
        float x2 = row[base + 32 + j];
        row[base + j]      = x1 * cv - x2 * sv;
        row[base + 32 + j] = x2 * cv + x1 * sv;
    }
}

// one block per (head, query row); block-diffusion mask computed analytically
__global__ void k_attn(const float* __restrict__ qkv, float* __restrict__ o) {
    int h = blockIdx.x >> 11;          // S = 2048
    int qi = blockIdx.x & (SS - 1);
    int tid = threadIdx.x;
    __shared__ float qs[HDIM];
    __shared__ float sc[SS];
    __shared__ float red[256];
    if (tid < HDIM) qs[tid] = qkv[(size_t)qi * 3 * DD + h * HDIM + tid];
    __syncthreads();
    bool fq = qi >= NN;
    int bq = (fq ? qi - NN : qi) >> 4;   // BS = 16
    float lmax = -INFINITY;
    for (int k = tid; k < SS; k += 256) {
        bool fk = k >= NN;
        int bk = (fk ? k - NN : k) >> 4;
        bool allowed = (bq == bk && fq == fk) || (fk && !fq && bq > bk) ||
                       (fk && fq && bq >= bk);
        float sval = -INFINITY;
        if (allowed) {
            const float* kr = qkv + (size_t)k * 3 * DD + DD + h * HDIM;
            float sdot = 0.f;
            for (int d = 0; d < HDIM; ++d) sdot += qs[d] * kr[d];
            sval = sdot * 0.125f;
        }
        sc[k] = sval;
        lmax = fmaxf(lmax, sval);
    }
    red[tid] = lmax; __syncthreads();
    for (int off = 128; off > 0; off >>= 1) {
        if (tid < off) red[tid] = fmaxf(red[tid], red[tid + off]);
        __syncthreads();
    }
    float m = red[0];
    __syncthreads();
    float lsum = 0.f;
    for (int k = tid; k < SS; k += 256) {
        float e = expf(sc[k] - m);
        sc[k] = e;
        lsum += e;
    }
    red[tid] = lsum; __syncthreads();
    for (int off = 128; off > 0; off >>= 1) {
        if (tid < off) red[tid] += red[tid + off];
        __syncthreads();
    }
    float inv = 1.0f / red[0];
    __syncthreads();
    int d = tid & 63, g = tid >> 6;       // wave-uniform g -> uniform skip branch
    float acc = 0.f;
    for (int k = g; k < SS; k += 4) {
        float p = sc[k];
        if (p != 0.0f) acc += p * qkv[(size_t)k * 3 * DD + 2 * DD + h * HDIM + d];
    }
    red[tid] = acc; __syncthreads();
    if (g == 0)
        o[(size_t)qi * DD + h * HDIM + d] =
            (red[d] + red[64 + d] + red[128 + d] + red[192 + d]) * inv;
}

extern "C" void kernel_launch(void* const* d_in, const int* in_sizes, int n_in,
                              void* d_out, int out_size, void* d_ws, size_t ws_size,
                              hipStream_t stream) {
    const float* x          = (const float*)d_in[0];
    const float* c          = (const float*)d_in[1];
    const float* cosT       = (const float*)d_in[2];
    const float* sinT       = (const float*)d_in[3];
    const float* norm1_w    = (const float*)d_in[4];
    const float* qkv_w      = (const float*)d_in[5];
    const float* attn_out_w = (const float*)d_in[6];
    const float* norm2_w    = (const float*)d_in[7];
    const float* mlp_w1     = (const float*)d_in[8];
    const float* mlp_b1     = (const float*)d_in[9];
    const float* mlp_w2     = (const float*)d_in[10];
    const float* mlp_b2     = (const float*)d_in[11];
    const float* adaLN_w    = (const float*)d_in[12];
    const float* adaLN_b    = (const float*)d_in[13];
    float* out = (float*)d_out;

    float* ws = (float*)d_ws;
    float* mods = ws;  ws += 6 * DD;
    float* qkv  = ws;  ws += (size_t)SS * 3 * DD;
    float* m1   = ws;  ws += (size_t)SS * 4 * DD;
    float* bufA = ws;  ws += (size_t)SS * DD;   // h, then o
    float* bufB = ws;  ws += (size_t)SS * DD;   // x2
    float* bufC = ws;  ws += (size_t)SS * DD;   // h2

    float* h  = bufA;
    float* o  = bufA;   // h dead after QKV GEMM
    float* x2 = bufB;
    float* h2 = bufC;

    k_adaln<<<6 * DD / 256, 256, 0, stream>>>(c, adaLN_w, adaLN_b, mods);
    k_ln_mod<<<SS, 256, 0, stream>>>(x, norm1_w, mods, 0, 1, h);

    dim3 g1(3 * DD / 64, SS / 64);
    k_gemm<0><<<g1, 256, 0, stream>>>(h, qkv_w, nullptr, nullptr, nullptr, qkv,
                                      SS, 3 * DD, DD);
    k_rope<<<SS, 256, 0, stream>>>(qkv, cosT, sinT);
    k_attn<<<HH * SS, 256, 0, stream>>>(qkv, o);

    dim3 g2(DD / 64, SS / 64);
    k_gemm<1><<<g2, 256, 0, stream>>>(o, attn_out_w, nullptr, mods + 2 * DD, x, x2,
                                      SS, DD, DD);
    k_ln_mod<<<SS, 256, 0, stream>>>(x2, norm2_w, mods, 3, 4, h2);

    dim3 g3(4 * DD / 64, SS / 64);
    k_gemm<2><<<g3, 256, 0, stream>>>(h2, mlp_w1, mlp_b1, nullptr, nullptr, m1,
                                      SS, 4 * DD, DD);
    dim3 g4(DD / 64, SS / 64);
    k_gemm<3><<<g4, 256, 0, stream>>>(m1, mlp_w2, mlp_b2, mods + 5 * DD, x2, out,
                                      SS, DD, 4 * DD);
}

// Round 2
// 954.801 us; speedup vs baseline: 2.3124x; 2.3124x over previous
//
#include <hip/hip_runtime.h>
#include <math.h>

#define SS 2048
#define NN 1024
#define DD 1024
#define HH 16
#define HDIM 64
#define CONDD 128

__device__ __forceinline__ float gelu_tanh(float x) {
    float x3 = x * x * x;
    return 0.5f * x * (1.0f + tanhf(0.79788456080286535588f * (x + 0.044715f * x3)));
}

// mods[6D] = adaLN_b + adaLN_w @ c      (W: [6D, COND] row-major)
__global__ void k_adaln(const float* __restrict__ c, const float* __restrict__ w,
                        const float* __restrict__ b, float* __restrict__ mods) {
    int o = blockIdx.x * 256 + threadIdx.x;
    float s = b[o];
    const float* wr = w + (size_t)o * CONDD;
    for (int k = 0; k < CONDD; ++k) s += c[k] * wr[k];
    mods[o] = s;
}

// out[row] = LN(x[row]) * w * (1 + mods[sc_idx*D + :]) + mods[sh_idx*D + :]
__global__ void k_ln_mod(const float* __restrict__ x, const float* __restrict__ w,
                         const float* __restrict__ mods, int sh_idx, int sc_idx,
                         float* __restrict__ out) {
    int row = blockIdx.x;
    int tid = threadIdx.x;
    const float* xr = x + (size_t)row * DD;
    float lx[4];
    float s = 0.f, s2 = 0.f;
    for (int i = 0; i < 4; ++i) {
        float v = xr[tid + i * 256];
        lx[i] = v; s += v; s2 += v * v;
    }
    __shared__ float rs[256], rs2[256];
    rs[tid] = s; rs2[tid] = s2; __syncthreads();
    for (int off = 128; off > 0; off >>= 1) {
        if (tid < off) { rs[tid] += rs[tid + off]; rs2[tid] += rs2[tid + off]; }
        __syncthreads();
    }
    float mu = rs[0] * (1.0f / DD);
    float var = rs2[0] * (1.0f / DD) - mu * mu;
    float rstd = rsqrtf(var + 1e-5f);
    const float* sh = mods + sh_idx * DD;
    const float* sc = mods + sc_idx * DD;
    float* orow = out + (size_t)row * DD;
    for (int i = 0; i < 4; ++i) {
        int d = tid + i * 256;
        orow[d] = (lx[i] - mu) * rstd * w[d] * (1.0f + sc[d]) + sh[d];
    }
}

// C[M, Nout] = A[M, K] @ W[Nout, K]^T  with fused epilogues
template <int MODE>
__global__ void k_gemm(const float* __restrict__ A, const float* __restrict__ W,
                       const float* __restrict__ bias, const float* __restrict__ gate,
                       const float* __restrict__ resid, float* __restrict__ C,
                       int M, int Nout, int K) {
    __shared__ __align__(16) float As[16][68];
    __shared__ __align__(16) float Ws[16][68];
    int tid = threadIdx.x;
    int tx = tid & 15, ty = tid >> 4;
    int n0 = blockIdx.x * 64, m0 = blockIdx.y * 64;
    float acc[4][4] = {};
    for (int k0 = 0; k0 < K; k0 += 16) {
        for (int i = 0; i < 4; ++i) {
            int idx = tid + i * 256;
            int r = idx >> 4, kk = idx & 15;
            As[kk][r] = A[(size_t)(m0 + r) * K + k0 + kk];
            Ws[kk][r] = W[(size_t)(n0 + r) * K + k0 + kk];
        }
        __syncthreads();
#pragma unroll
        for (int kk = 0; kk < 16; ++kk) {
            float4 a = *(const float4*)&As[kk][ty * 4];
            float4 b = *(const float4*)&Ws[kk][tx * 4];
            float av[4] = {a.x, a.y, a.z, a.w};
            float bv[4] = {b.x, b.y, b.z, b.w};
#pragma unroll
            for (int i = 0; i < 4; ++i)
#pragma unroll
                for (int j = 0; j < 4; ++j) acc[i][j] += av[i] * bv[j];
        }
        __syncthreads();
    }
    for (int i = 0; i < 4; ++i) {
        int m = m0 + ty * 4 + i;
        float outv[4];
        for (int j = 0; j < 4; ++j) {
            int n = n0 + tx * 4 + j;
            float v = acc[i][j];
            if (MODE == 1) v = gate[n] * v + resid[(size_t)m * Nout + n];
            if (MODE == 2) v = gelu_tanh(v + bias[n]);
            if (MODE == 3) v = gate[n] * (v + bias[n]) + resid[(size_t)m * Nout + n];
            outv[j] = v;
        }
        *(float4*)&C[(size_t)m * Nout + n0 + tx * 4] = *(float4*)outv;
    }
}

// in-place RoPE on qkv [S, 3, H, HD]; applied to q, k AND v; pos = s mod N
__global__ void k_rope(float* __restrict__ qkv, const float* __restrict__ cosT,
                       const float* __restrict__ sinT) {
    int s = blockIdx.x;
    int pos = s & (NN - 1);
    float* row = qkv + (size_t)s * 3 * DD;
    for (int p = threadIdx.x; p < 3 * HH * 32; p += 256) {
        int j = p & 31;
        int head = p >> 5;
        int base = head * HDIM;
        float cv = cosT[pos * 32 + j];
        float sv = sinT[pos * 32 + j];
        float x1 = row[base + j];
        float x2 = row[base + 32 + j];
        row[base + j]      = x1 * cv - x2 * sv;
        row[base + 32 + j] = x2 * cv + x1 * sv;
    }
}

// Tiled flash attention over the block-diffusion mask.
// Mask is block-granular (BS=16): for q-block bq in {noisy, clean} half:
//   noisy: allowed key-tiles = {noisy diag bq} U {clean tiles 0..bq-1}  (bq+1 tiles)
//   clean: allowed key-tiles = {clean tiles 0..bq}                      (bq+1 tiles)
// Pair q-blocks (bq, 63-bq) in one workgroup -> every block has exactly 65 tiles.
__global__ void k_attn2(const float* __restrict__ qkv, float* __restrict__ o) {
    __shared__ __align__(16) float Qs[16][68];
    __shared__ __align__(16) float Ks[16][68];
    __shared__ __align__(16) float Vs[16][68];
    __shared__ float Ps[16][16];
    int tid = threadIdx.x;
    int tx = tid & 15, ty = tid >> 4;
    int h = blockIdx.x >> 6;
    int jj = blockIdx.x & 63;
    int half = jj >> 5;              // 0 = noisy q, 1 = clean q
    int pi = jj & 31;
    int ldr = tid >> 4;              // load row
    int ldc = (tid & 15) * 4;        // load col (float4)

    for (int sel = 0; sel < 2; ++sel) {
        int bq = (sel == 0) ? pi : 63 - pi;
        int q0 = (half == 0) ? bq * 16 : NN + bq * 16;
        {
            const float* src = qkv + (size_t)(q0 + ldr) * 3 * DD + h * HDIM + ldc;
            *(float4*)&Qs[ldr][ldc] = *(const float4*)src;
        }
        float m = -INFINITY, l = 0.f;
        float acc0 = 0.f, acc1 = 0.f, acc2 = 0.f, acc3 = 0.f;
        int ntiles = bq + 1;
        __syncthreads();
        for (int t = 0; t < ntiles; ++t) {
            int kbase;
            if (half == 0) kbase = (t == 0) ? bq * 16 : NN + (t - 1) * 16;
            else           kbase = NN + t * 16;
            const float* kv = qkv + (size_t)(kbase + ldr) * 3 * DD + h * HDIM + ldc;
            *(float4*)&Ks[ldr][ldc] = *(const float4*)(kv + DD);
            *(float4*)&Vs[ldr][ldc] = *(const float4*)(kv + 2 * DD);
            __syncthreads();
            // s = Q[ty] . K[tx]
            float s = 0.f;
#pragma unroll
            for (int d = 0; d < 64; d += 4) {
                float4 qv = *(const float4*)&Qs[ty][d];
                float4 kk = *(const float4*)&Ks[tx][d];
                s += qv.x * kk.x + qv.y * kk.y + qv.z * kk.z + qv.w * kk.w;
            }
            s *= 0.125f;
            float rmax = s;
            rmax = fmaxf(rmax, __shfl_xor(rmax, 1));
            rmax = fmaxf(rmax, __shfl_xor(rmax, 2));
            rmax = fmaxf(rmax, __shfl_xor(rmax, 4));
            rmax = fmaxf(rmax, __shfl_xor(rmax, 8));
            float m_new = fmaxf(m, rmax);
            float p = __expf(s - m_new);
            float rsum = p;
            rsum += __shfl_xor(rsum, 1);
            rsum += __shfl_xor(rsum, 2);
            rsum += __shfl_xor(rsum, 4);
            rsum += __shfl_xor(rsum, 8);
            float alpha = __expf(m - m_new);
            m = m_new;
            l = l * alpha + rsum;
            Ps[ty][tx] = p;
            acc0 *= alpha; acc1 *= alpha; acc2 *= alpha; acc3 *= alpha;
            __syncthreads();
#pragma unroll
            for (int k = 0; k < 16; ++k) {
                float pk = Ps[ty][k];
                float4 vv = *(const float4*)&Vs[k][tx * 4];
                acc0 += pk * vv.x; acc1 += pk * vv.y;
                acc2 += pk * vv.z; acc3 += pk * vv.w;
            }
            __syncthreads();
        }
        float inv = 1.0f / l;
        float4 outv = {acc0 * inv, acc1 * inv, acc2 * inv, acc3 * inv};
        *(float4*)&o[(size_t)(q0 + ty) * DD + h * HDIM + tx * 4] = outv;
    }
}

extern "C" void kernel_launch(void* const* d_in, const int* in_sizes, int n_in,
                              void* d_out, int out_size, void* d_ws, size_t ws_size,
                              hipStream_t stream) {
    const float* x          = (const float*)d_in[0];
    const float* c          = (const float*)d_in[1];
    const float* cosT       = (const float*)d_in[2];
    const float* sinT       = (const float*)d_in[3];
    const float* norm1_w    = (const float*)d_in[4];
    const float* qkv_w      = (const float*)d_in[5];
    const float* attn_out_w = (const float*)d_in[6];
    const float* norm2_w    = (const float*)d_in[7];
    const float* mlp_w1     = (const float*)d_in[8];
    const float* mlp_b1     = (const float*)d_in[9];
    const float* mlp_w2     = (const float*)d_in[10];
    const float* mlp_b2     = (const float*)d_in[11];
    const float* adaLN_w    = (const float*)d_in[12];
    const float* adaLN_b    = (const float*)d_in[13];
    float* out = (float*)d_out;

    float* ws = (float*)d_ws;
    float* mods = ws;  ws += 6 * DD;
    float* qkv  = ws;  ws += (size_t)SS * 3 * DD;
    float* m1   = ws;  ws += (size_t)SS * 4 * DD;
    float* bufA = ws;  ws += (size_t)SS * DD;   // h, then o
    float* bufB = ws;  ws += (size_t)SS * DD;   // x2
    float* bufC = ws;  ws += (size_t)SS * DD;   // h2

    float* h  = bufA;
    float* o  = bufA;   // h dead after QKV GEMM
    float* x2 = bufB;
    float* h2 = bufC;

    k_adaln<<<6 * DD / 256, 256, 0, stream>>>(c, adaLN_w, adaLN_b, mods);
    k_ln_mod<<<SS, 256, 0, stream>>>(x, norm1_w, mods, 0, 1, h);

    dim3 g1(3 * DD / 64, SS / 64);
    k_gemm<0><<<g1, 256, 0, stream>>>(h, qkv_w, nullptr, nullptr, nullptr, qkv,
                                      SS, 3 * DD, DD);
    k_rope<<<SS, 256, 0, stream>>>(qkv, cosT, sinT);
    k_attn2<<<HH * 64, 256, 0, stream>>>(qkv, o);

    dim3 g2(DD / 64, SS / 64);
    k_gemm<1><<<g2, 256, 0, stream>>>(o, attn_out_w, nullptr, mods + 2 * DD, x, x2,
                                      SS, DD, DD);
    k_ln_mod<<<SS, 256, 0, stream>>>(x2, norm2_w, mods, 3, 4, h2);

    dim3 g3(4 * DD / 64, SS / 64);
    k_gemm<2><<<g3, 256, 0, stream>>>(h2, mlp_w1, mlp_b1, nullptr, nullptr, m1,
                                      SS, 4 * DD, DD);
    dim3 g4(DD / 64, SS / 64);
    k_gemm<3><<<g4, 256, 0, stream>>>(m1, mlp_w2, mlp_b2, mods + 5 * DD, x2, out,
                                      SS, DD, 4 * DD);
}

// Round 3
// 336.959 us; speedup vs baseline: 6.5523x; 2.8336x over previous
//
#include <hip/hip_runtime.h>
#include <math.h>

#define SS 2048
#define NN 1024
#define DD 1024
#define HH 16
#define HDIM 64
#define CONDD 128

typedef unsigned short ushort;
typedef unsigned int uint;
typedef __bf16 bf16x8 __attribute__((ext_vector_type(8)));
typedef float f32x4 __attribute__((ext_vector_type(4)));

__device__ __forceinline__ float gelu_tanh(float x) {
    float x3 = x * x * x;
    return 0.5f * x * (1.0f + tanhf(0.79788456080286535588f * (x + 0.044715f * x3)));
}

__device__ __forceinline__ ushort f2bf(float x) {
    uint u = __float_as_uint(x);
    u += 0x7fff + ((u >> 16) & 1);
    return (ushort)(u >> 16);
}

__device__ __forceinline__ void gload16(const ushort* g, ushort* l) {
    __builtin_amdgcn_global_load_lds(
        (const __attribute__((address_space(1))) void*)g,
        (__attribute__((address_space(3))) void*)l, 16, 0, 0);
}

// fp32 -> bf16 (RNE), n multiple of 4
__global__ void k_cast(const float* __restrict__ in, ushort* __restrict__ out, int n) {
    int i = (blockIdx.x * 256 + threadIdx.x) * 4;
    if (i >= n) return;
    float4 v = *(const float4*)(in + i);
    ushort4 o = {f2bf(v.x), f2bf(v.y), f2bf(v.z), f2bf(v.w)};
    *(ushort4*)(out + i) = o;
}

// mods[6D] = adaLN_b + adaLN_w @ c
__global__ void k_adaln(const float* __restrict__ c, const float* __restrict__ w,
                        const float* __restrict__ b, float* __restrict__ mods) {
    int o = blockIdx.x * 256 + threadIdx.x;
    float s = b[o];
    const float* wr = w + (size_t)o * CONDD;
    for (int k = 0; k < CONDD; ++k) s += c[k] * wr[k];
    mods[o] = s;
}

// out(bf16)[row] = LN(x[row]) * w * (1 + mods[sc*D+:]) + mods[sh*D+:]
__global__ void k_ln_mod(const float* __restrict__ x, const float* __restrict__ w,
                         const float* __restrict__ mods, int sh_idx, int sc_idx,
                         ushort* __restrict__ out) {
    int row = blockIdx.x;
    int tid = threadIdx.x;
    const float* xr = x + (size_t)row * DD;
    float lx[4];
    float s = 0.f, s2 = 0.f;
    for (int i = 0; i < 4; ++i) {
        float v = xr[tid + i * 256];
        lx[i] = v; s += v; s2 += v * v;
    }
    __shared__ float rs[256], rs2[256];
    rs[tid] = s; rs2[tid] = s2; __syncthreads();
    for (int off = 128; off > 0; off >>= 1) {
        if (tid < off) { rs[tid] += rs[tid + off]; rs2[tid] += rs2[tid + off]; }
        __syncthreads();
    }
    float mu = rs[0] * (1.0f / DD);
    float var = rs2[0] * (1.0f / DD) - mu * mu;
    float rstd = rsqrtf(var + 1e-5f);
    const float* sh = mods + sh_idx * DD;
    const float* sc = mods + sc_idx * DD;
    ushort* orow = out + (size_t)row * DD;
    for (int i = 0; i < 4; ++i) {
        int d = tid + i * 256;
        orow[d] = f2bf((lx[i] - mu) * rstd * w[d] * (1.0f + sc[d]) + sh[d]);
    }
}

// C[M,N] = A[M,K](bf16) @ W[N,K](bf16)^T, fp32 accum, fused epilogue.
// 128x128 tile, BK=64, 4 waves -> 64x64 quadrant each, mfma_f32_16x16x32_bf16.
// LDS XOR swizzle: 16B chunk kc at row r stored at position kc^(r&7); staged via
// pre-swizzled GLOBAL source + linear LDS dest (global_load_lds constraint).
// MODE 0: C=acc (float)   MODE 1: C=gate[n]*acc+resid (float)
// MODE 2: C=gelu(acc+bias[n]) (bf16)   MODE 3: C=gate[n]*(acc+bias[n])+resid (float)
template <int MODE, typename OT>
__global__ void k_gemm_mfma(const ushort* __restrict__ A, const ushort* __restrict__ W,
                            const float* __restrict__ bias, const float* __restrict__ gate,
                            const float* __restrict__ resid, OT* __restrict__ C,
                            int M, int Nout, int K) {
    __shared__ ushort lA[128 * 64];
    __shared__ ushort lB[128 * 64];
    int tid = threadIdx.x;
    int lane = tid & 63, wave = tid >> 6;
    int wr = wave >> 1, wc = wave & 1;
    int l15 = lane & 15, l4 = lane >> 4;
    int n0 = blockIdx.x * 128, m0 = blockIdx.y * 128;

    f32x4 acc[4][4] = {};

    for (int k0 = 0; k0 < K; k0 += 64) {
#pragma unroll
        for (int i = 0; i < 4; ++i) {
            int cb = (wave * 4 + i) * 64;          // slot of lane 0 (wave-uniform)
            int s = cb + lane;
            int row = s >> 3;
            int kc = (s & 7) ^ (row & 7);          // pre-swizzled global chunk
            gload16(A + (size_t)(m0 + row) * K + k0 + kc * 8, lA + (size_t)cb * 8);
            gload16(W + (size_t)(n0 + row) * K + k0 + kc * 8, lB + (size_t)cb * 8);
        }
        __syncthreads();                            // drains vmcnt before barrier
#pragma unroll
        for (int sub = 0; sub < 2; ++sub) {
            bf16x8 af[4], bw[4];
#pragma unroll
            for (int mi = 0; mi < 4; ++mi) {
                int row = wr * 64 + mi * 16 + l15;
                int pos = ((sub << 2) | l4) ^ (row & 7);
                af[mi] = *(const bf16x8*)&lA[row * 64 + pos * 8];
            }
#pragma unroll
            for (int ni = 0; ni < 4; ++ni) {
                int row = wc * 64 + ni * 16 + l15;
                int pos = ((sub << 2) | l4) ^ (row & 7);
                bw[ni] = *(const bf16x8*)&lB[row * 64 + pos * 8];
            }
#pragma unroll
            for (int mi = 0; mi < 4; ++mi)
#pragma unroll
                for (int ni = 0; ni < 4; ++ni)
                    acc[mi][ni] = __builtin_amdgcn_mfma_f32_16x16x32_bf16(
                        af[mi], bw[ni], acc[mi][ni], 0, 0, 0);
        }
        __syncthreads();
    }

#pragma unroll
    for (int mi = 0; mi < 4; ++mi) {
#pragma unroll
        for (int r = 0; r < 4; ++r) {
            int m = m0 + wr * 64 + mi * 16 + l4 * 4 + r;
#pragma unroll
            for (int ni = 0; ni < 4; ++ni) {
                int n = n0 + wc * 64 + ni * 16 + l15;
                float v = acc[mi][ni][r];
                if (MODE == 1) v = gate[n] * v + resid[(size_t)m * Nout + n];
                if (MODE == 2) v = gelu_tanh(v + bias[n]);
                if (MODE == 3) v = gate[n] * (v + bias[n]) + resid[(size_t)m * Nout + n];
                if (sizeof(OT) == 2) C[(size_t)m * Nout + n] = (OT)f2bf(v);
                else                 C[(size_t)m * Nout + n] = (OT)v;
            }
        }
    }
}

// in-place RoPE on qkv [S, 3, H, HD] fp32; applied to q, k AND v; pos = s mod N
__global__ void k_rope(float* __restrict__ qkv, const float* __restrict__ cosT,
                       const float* __restrict__ sinT) {
    int s = blockIdx.x;
    int pos = s & (NN - 1);
    float* row = qkv + (size_t)s * 3 * DD;
    for (int p = threadIdx.x; p < 3 * HH * 32; p += 256) {
        int j = p & 31;
        int head = p >> 5;
        int base = head * HDIM;
        float cv = cosT[pos * 32 + j];
        float sv = sinT[pos * 32 + j];
        float x1 = row[base + j];
        float x2 = row[base + 32 + j];
        row[base + j]      = x1 * cv - x2 * sv;
        row[base + 32 + j] = x2 * cv + x1 * sv;
    }
}

// Tiled flash attention over block-diffusion mask (block-granular, BS=16).
// Pair q-blocks (bq, 63-bq) -> every workgroup has exactly 65 key-tiles.
__global__ void k_attn2(const float* __restrict__ qkv, ushort* __restrict__ o) {
    __shared__ __align__(16) float Qs[16][68];
    __shared__ __align__(16) float Ks[16][68];
    __shared__ __align__(16) float Vs[16][68];
    __shared__ float Ps[16][16];
    int tid = threadIdx.x;
    int tx = tid & 15, ty = tid >> 4;
    int h = blockIdx.x >> 6;
    int jj = blockIdx.x & 63;
    int half = jj >> 5;
    int pi = jj & 31;
    int ldr = tid >> 4;
    int ldc = (tid & 15) * 4;

    for (int sel = 0; sel < 2; ++sel) {
        int bq = (sel == 0) ? pi : 63 - pi;
        int q0 = (half == 0) ? bq * 16 : NN + bq * 16;
        {
            const float* src = qkv + (size_t)(q0 + ldr) * 3 * DD + h * HDIM + ldc;
            *(float4*)&Qs[ldr][ldc] = *(const float4*)src;
        }
        float m = -INFINITY, l = 0.f;
        float acc0 = 0.f, acc1 = 0.f, acc2 = 0.f, acc3 = 0.f;
        int ntiles = bq + 1;
        __syncthreads();
        for (int t = 0; t < ntiles; ++t) {
            int kbase;
            if (half == 0) kbase = (t == 0) ? bq * 16 : NN + (t - 1) * 16;
            else           kbase = NN + t * 16;
            const float* kv = qkv + (size_t)(kbase + ldr) * 3 * DD + h * HDIM + ldc;
            *(float4*)&Ks[ldr][ldc] = *(const float4*)(kv + DD);
            *(float4*)&Vs[ldr][ldc] = *(const float4*)(kv + 2 * DD);
            __syncthreads();
            float s = 0.f;
#pragma unroll
            for (int d = 0; d < 64; d += 4) {
                float4 qv = *(const float4*)&Qs[ty][d];
                float4 kk = *(const float4*)&Ks[tx][d];
                s += qv.x * kk.x + qv.y * kk.y + qv.z * kk.z + qv.w * kk.w;
            }
            s *= 0.125f;
            float rmax = s;
            rmax = fmaxf(rmax, __shfl_xor(rmax, 1));
            rmax = fmaxf(rmax, __shfl_xor(rmax, 2));
            rmax = fmaxf(rmax, __shfl_xor(rmax, 4));
            rmax = fmaxf(rmax, __shfl_xor(rmax, 8));
            float m_new = fmaxf(m, rmax);
            float p = __expf(s - m_new);
            float rsum = p;
            rsum += __shfl_xor(rsum, 1);
            rsum += __shfl_xor(rsum, 2);
            rsum += __shfl_xor(rsum, 4);
            rsum += __shfl_xor(rsum, 8);
            float alpha = __expf(m - m_new);
            m = m_new;
            l = l * alpha + rsum;
            Ps[ty][tx] = p;
            acc0 *= alpha; acc1 *= alpha; acc2 *= alpha; acc3 *= alpha;
            __syncthreads();
#pragma unroll
            for (int k = 0; k < 16; ++k) {
                float pk = Ps[ty][k];
                float4 vv = *(const float4*)&Vs[k][tx * 4];
                acc0 += pk * vv.x; acc1 += pk * vv.y;
                acc2 += pk * vv.z; acc3 += pk * vv.w;
            }
            __syncthreads();
        }
        float inv = 1.0f / l;
        ushort4 ov = {f2bf(acc0 * inv), f2bf(acc1 * inv), f2bf(acc2 * inv), f2bf(acc3 * inv)};
        *(ushort4*)&o[(size_t)(q0 + ty) * DD + h * HDIM + tx * 4] = ov;
    }
}

extern "C" void kernel_launch(void* const* d_in, const int* in_sizes, int n_in,
                              void* d_out, int out_size, void* d_ws, size_t ws_size,
                              hipStream_t stream) {
    const float* x          = (const float*)d_in[0];
    const float* c          = (const float*)d_in[1];
    const float* cosT       = (const float*)d_in[2];
    const float* sinT       = (const float*)d_in[3];
    const float* norm1_w    = (const float*)d_in[4];
    const float* qkv_w      = (const float*)d_in[5];
    const float* attn_out_w = (const float*)d_in[6];
    const float* norm2_w    = (const float*)d_in[7];
    const float* mlp_w1     = (const float*)d_in[8];
    const float* mlp_b1     = (const float*)d_in[9];
    const float* mlp_w2     = (const float*)d_in[10];
    const float* mlp_b2     = (const float*)d_in[11];
    const float* adaLN_w    = (const float*)d_in[12];
    const float* adaLN_b    = (const float*)d_in[13];
    float* out = (float*)d_out;

    char* p = (char*)d_ws;
    float*  mods = (float*)p;   p += 6 * DD * 4;
    float*  qkv  = (float*)p;   p += (size_t)SS * 3 * DD * 4;   // 24 MB
    float*  x2   = (float*)p;   p += (size_t)SS * DD * 4;       // 8 MB
    ushort* hbuf = (ushort*)p;  p += (size_t)SS * DD * 2;       // h, then h2
    ushort* obuf = (ushort*)p;  p += (size_t)SS * DD * 2;
    ushort* wq   = (ushort*)p;  p += (size_t)3 * DD * DD * 2;
    ushort* wo   = (ushort*)p;  p += (size_t)DD * DD * 2;
    ushort* w1   = (ushort*)p;  p += (size_t)4 * DD * DD * 2;
    ushort* w2   = (ushort*)p;  p += (size_t)4 * DD * DD * 2;
    ushort* m1   = (ushort*)qkv;   // alias: qkv dead after k_attn2

    // weight casts (fp32 -> bf16)
    k_cast<<<(3 * DD * DD) / 1024, 256, 0, stream>>>(qkv_w, wq, 3 * DD * DD);
    k_cast<<<(DD * DD) / 1024, 256, 0, stream>>>(attn_out_w, wo, DD * DD);
    k_cast<<<(4 * DD * DD) / 1024, 256, 0, stream>>>(mlp_w1, w1, 4 * DD * DD);
    k_cast<<<(4 * DD * DD) / 1024, 256, 0, stream>>>(mlp_w2, w2, 4 * DD * DD);

    k_adaln<<<6 * DD / 256, 256, 0, stream>>>(c, adaLN_w, adaLN_b, mods);
    k_ln_mod<<<SS, 256, 0, stream>>>(x, norm1_w, mods, 0, 1, hbuf);

    dim3 g1(3 * DD / 128, SS / 128);
    k_gemm_mfma<0, float><<<g1, 256, 0, stream>>>(hbuf, wq, nullptr, nullptr, nullptr,
                                                  qkv, SS, 3 * DD, DD);
    k_rope<<<SS, 256, 0, stream>>>(qkv, cosT, sinT);
    k_attn2<<<HH * 64, 256, 0, stream>>>(qkv, obuf);

    dim3 g2(DD / 128, SS / 128);
    k_gemm_mfma<1, float><<<g2, 256, 0, stream>>>(obuf, wo, nullptr, mods + 2 * DD, x,
                                                  x2, SS, DD, DD);
    k_ln_mod<<<SS, 256, 0, stream>>>(x2, norm2_w, mods, 3, 4, hbuf);

    dim3 g3(4 * DD / 128, SS / 128);
    k_gemm_mfma<2, ushort><<<g3, 256, 0, stream>>>(hbuf, w1, mlp_b1, nullptr, nullptr,
                                                   m1, SS, 4 * DD, DD);
    dim3 g4(DD / 128, SS / 128);
    k_gemm_mfma<3, float><<<g4, 256, 0, stream>>>(m1, w2, mlp_b2, mods + 5 * DD, x2,
                                                  out, SS, DD, 4 * DD);
}

// Round 4
// 217.803 us; speedup vs baseline: 10.1370x; 1.5471x over previous
//
#include <hip/hip_runtime.h>
#include <math.h>

#define SS 2048
#define NN 1024
#define DD 1024
#define HH 16
#define CONDD 128

typedef unsigned short ushort;
typedef unsigned int uint;
typedef __bf16 bf16x8 __attribute__((ext_vector_type(8)));
typedef float f32x4 __attribute__((ext_vector_type(4)));
typedef short s16x4 __attribute__((ext_vector_type(4)));
typedef ushort u16x8 __attribute__((ext_vector_type(8)));

__device__ __forceinline__ float gelu_tanh(float x) {
    float x3 = x * x * x;
    return 0.5f * x * (1.0f + tanhf(0.79788456080286535588f * (x + 0.044715f * x3)));
}

__device__ __forceinline__ ushort f2bf(float x) {
    uint u = __float_as_uint(x);
    u += 0x7fff + ((u >> 16) & 1);
    return (ushort)(u >> 16);
}

__device__ __forceinline__ float bf2f(ushort u) {
    return __uint_as_float(((uint)u) << 16);
}

__device__ __forceinline__ void gload16(const ushort* g, ushort* l) {
    __builtin_amdgcn_global_load_lds(
        (const __attribute__((address_space(1))) void*)g,
        (__attribute__((address_space(3))) void*)l, 16, 0, 0);
}

// 16x16x16 bf16 MFMA (PV step): A,B = 4 bf16 (2 VGPR), C/D = 4 f32
__device__ __forceinline__ f32x4 mfma16(s16x4 a, s16x4 b, f32x4 c) {
#if __has_builtin(__builtin_amdgcn_mfma_f32_16x16x16bf16_1k)
    return __builtin_amdgcn_mfma_f32_16x16x16bf16_1k(a, b, c, 0, 0, 0);
#else
    asm("v_mfma_f32_16x16x16_bf16 %0, %1, %2, %0" : "+v"(c) : "v"(a), "v"(b));
    return c;
#endif
}

// fp32 -> bf16 (RNE), n multiple of 4
__global__ void k_cast(const float* __restrict__ in, ushort* __restrict__ out, int n) {
    int i = (blockIdx.x * 256 + threadIdx.x) * 4;
    if (i >= n) return;
    float4 v = *(const float4*)(in + i);
    ushort4 o = {f2bf(v.x), f2bf(v.y), f2bf(v.z), f2bf(v.w)};
    *(ushort4*)(out + i) = o;
}

// mods[6D] = adaLN_b + adaLN_w @ c
__global__ void k_adaln(const float* __restrict__ c, const float* __restrict__ w,
                        const float* __restrict__ b, float* __restrict__ mods) {
    int o = blockIdx.x * 256 + threadIdx.x;
    float s = b[o];
    const float* wr = w + (size_t)o * CONDD;
    for (int k = 0; k < CONDD; ++k) s += c[k] * wr[k];
    mods[o] = s;
}

// out(bf16)[row] = LN(x[row]) * w * (1 + mods[sc*D+:]) + mods[sh*D+:]
__global__ void k_ln_mod(const float* __restrict__ x, const float* __restrict__ w,
                         const float* __restrict__ mods, int sh_idx, int sc_idx,
                         ushort* __restrict__ out) {
    int row = blockIdx.x;
    int tid = threadIdx.x;
    const float* xr = x + (size_t)row * DD;
    float lx[4];
    float s = 0.f, s2 = 0.f;
    for (int i = 0; i < 4; ++i) {
        float v = xr[tid + i * 256];
        lx[i] = v; s += v; s2 += v * v;
    }
    __shared__ float rs[256], rs2[256];
    rs[tid] = s; rs2[tid] = s2; __syncthreads();
    for (int off = 128; off > 0; off >>= 1) {
        if (tid < off) { rs[tid] += rs[tid + off]; rs2[tid] += rs2[tid + off]; }
        __syncthreads();
    }
    float mu = rs[0] * (1.0f / DD);
    float var = rs2[0] * (1.0f / DD) - mu * mu;
    float rstd = rsqrtf(var + 1e-5f);
    const float* sh = mods + sh_idx * DD;
    const float* sc = mods + sc_idx * DD;
    ushort* orow = out + (size_t)row * DD;
    for (int i = 0; i < 4; ++i) {
        int d = tid + i * 256;
        orow[d] = f2bf((lx[i] - mu) * rstd * w[d] * (1.0f + sc[d]) + sh[d]);
    }
}

// C[M,N] = A[M,K](bf16) @ W[N,K](bf16)^T, fp32 accum, fused epilogue.
// 128x128 tile, BK=64, 4 waves, mfma_f32_16x16x32_bf16, XOR-swizzled LDS.
template <int MODE, typename OT>
__global__ void k_gemm_mfma(const ushort* __restrict__ A, const ushort* __restrict__ W,
                            const float* __restrict__ bias, const float* __restrict__ gate,
                            const float* __restrict__ resid, OT* __restrict__ C,
                            int M, int Nout, int K) {
    __shared__ ushort lA[128 * 64];
    __shared__ ushort lB[128 * 64];
    int tid = threadIdx.x;
    int lane = tid & 63, wave = tid >> 6;
    int wr = wave >> 1, wc = wave & 1;
    int l15 = lane & 15, l4 = lane >> 4;
    int n0 = blockIdx.x * 128, m0 = blockIdx.y * 128;

    f32x4 acc[4][4] = {};

    for (int k0 = 0; k0 < K; k0 += 64) {
#pragma unroll
        for (int i = 0; i < 4; ++i) {
            int cb = (wave * 4 + i) * 64;
            int s = cb + lane;
            int row = s >> 3;
            int kc = (s & 7) ^ (row & 7);
            gload16(A + (size_t)(m0 + row) * K + k0 + kc * 8, lA + (size_t)cb * 8);
            gload16(W + (size_t)(n0 + row) * K + k0 + kc * 8, lB + (size_t)cb * 8);
        }
        __syncthreads();
#pragma unroll
        for (int sub = 0; sub < 2; ++sub) {
            bf16x8 af[4], bw[4];
#pragma unroll
            for (int mi = 0; mi < 4; ++mi) {
                int row = wr * 64 + mi * 16 + l15;
                int pos = ((sub << 2) | l4) ^ (row & 7);
                af[mi] = *(const bf16x8*)&lA[row * 64 + pos * 8];
            }
#pragma unroll
            for (int ni = 0; ni < 4; ++ni) {
                int row = wc * 64 + ni * 16 + l15;
                int pos = ((sub << 2) | l4) ^ (row & 7);
                bw[ni] = *(const bf16x8*)&lB[row * 64 + pos * 8];
            }
#pragma unroll
            for (int mi = 0; mi < 4; ++mi)
#pragma unroll
                for (int ni = 0; ni < 4; ++ni)
                    acc[mi][ni] = __builtin_amdgcn_mfma_f32_16x16x32_bf16(
                        af[mi], bw[ni], acc[mi][ni], 0, 0, 0);
        }
        __syncthreads();
    }

#pragma unroll
    for (int mi = 0; mi < 4; ++mi) {
#pragma unroll
        for (int r = 0; r < 4; ++r) {
            int m = m0 + wr * 64 + mi * 16 + l4 * 4 + r;
#pragma unroll
            for (int ni = 0; ni < 4; ++ni) {
                int n = n0 + wc * 64 + ni * 16 + l15;
                float v = acc[mi][ni][r];
                if (MODE == 1) v = gate[n] * v + resid[(size_t)m * Nout + n];
                if (MODE == 2) v = gelu_tanh(v + bias[n]);
                if (MODE == 3) v = gate[n] * (v + bias[n]) + resid[(size_t)m * Nout + n];
                if (sizeof(OT) == 2) C[(size_t)m * Nout + n] = (OT)f2bf(v);
                else                 C[(size_t)m * Nout + n] = (OT)v;
            }
        }
    }
}

// RoPE on bf16 qkv [s][3][H][64] -> qb[s][D] (scaled by 0.125*log2e), kb[s][D],
// vT[h][d][s] (transposed via LDS). RoPE applied to q, k AND v; pos = s mod N.
__global__ void k_rope2(const ushort* __restrict__ qkvb, const float* __restrict__ cosT,
                        const float* __restrict__ sinT, ushort* __restrict__ qb,
                        ushort* __restrict__ kb, ushort* __restrict__ vT) {
    __shared__ ushort vt[64][65];
    int h = blockIdx.x & 15;
    int st = blockIdx.x >> 4;
    int s0 = st * 64;
    int tid = threadIdx.x;
#pragma unroll
    for (int i = 0; i < 8; ++i) {
        int idx = tid + i * 256;
        int sl = idx >> 5, j = idx & 31;
        int s = s0 + sl;
        int pos = s & (NN - 1);
        float cv = cosT[pos * 32 + j], sv = sinT[pos * 32 + j];
        const ushort* row = qkvb + (size_t)s * 3072 + h * 64;
        float x1 = bf2f(row[j]), x2 = bf2f(row[j + 32]);
        qb[(size_t)s * DD + h * 64 + j]      = f2bf((x1 * cv - x2 * sv) * 0.18033688011f);
        qb[(size_t)s * DD + h * 64 + j + 32] = f2bf((x2 * cv + x1 * sv) * 0.18033688011f);
        x1 = bf2f(row[1024 + j]); x2 = bf2f(row[1024 + j + 32]);
        kb[(size_t)s * DD + h * 64 + j]      = f2bf(x1 * cv - x2 * sv);
        kb[(size_t)s * DD + h * 64 + j + 32] = f2bf(x2 * cv + x1 * sv);
        x1 = bf2f(row[2048 + j]); x2 = bf2f(row[2048 + j + 32]);
        vt[sl][j]      = f2bf(x1 * cv - x2 * sv);
        vt[sl][j + 32] = f2bf(x2 * cv + x1 * sv);
    }
    __syncthreads();
    int drow = tid >> 2, sc = (tid & 3) * 16;
    u16x8 a, b;
#pragma unroll
    for (int i = 0; i < 8; ++i) { a[i] = vt[sc + i][drow]; b[i] = vt[sc + 8 + i][drow]; }
    size_t base = (size_t)(h * 64 + drow) * SS + s0 + sc;
    *(u16x8*)&vT[base] = a;
    *(u16x8*)&vT[base + 8] = b;
}

// MFMA flash attention over the block-diffusion mask (block-granular, BS=16).
// One wave per (head, bq); handles first-half AND second-half q-block bq,
// sharing second-half key tiles 0..bq-1 (loaded once, used for both states).
// Swapped QK: S^T = mfma_16x16x32(K_frag, Q_frag) -> lane: q=lane&15, key=l4*4+r.
// P^T regs are exactly the 16x16x16 B-frag -> PV with no cross-lane movement.
// Softmax in exp2 units (0.125*log2e folded into qb); defer-max THR=8.
struct KVTile { bf16x8 k0, k1; s16x4 v0, v1, v2, v3; };

__global__ __launch_bounds__(64) void k_attn3(
        const ushort* __restrict__ qb, const ushort* __restrict__ kb,
        const ushort* __restrict__ vT, ushort* __restrict__ o) {
    int id = blockIdx.x;
    int h = id & 15;
    int bq = 63 - (id >> 4);          // heavy-first
    int lane = threadIdx.x;
    int l15 = lane & 15, l4 = lane >> 4;
    int hb = h * 64;

    const int q0A = bq * 16, q0B = NN + bq * 16;
    bf16x8 qA0 = *(const bf16x8*)&qb[(size_t)(q0A + l15) * DD + hb + l4 * 8];
    bf16x8 qA1 = *(const bf16x8*)&qb[(size_t)(q0A + l15) * DD + hb + 32 + l4 * 8];
    bf16x8 qB0 = *(const bf16x8*)&qb[(size_t)(q0B + l15) * DD + hb + l4 * 8];
    bf16x8 qB1 = *(const bf16x8*)&qb[(size_t)(q0B + l15) * DD + hb + 32 + l4 * 8];

    float mA = -1e30f, lA = 0.f, mB = -1e30f, lB = 0.f;
    f32x4 oA0 = {}, oA1 = {}, oA2 = {}, oA3 = {};
    f32x4 oB0 = {}, oB1 = {}, oB2 = {}, oB3 = {};

    auto loadT = [&](int kbase) {
        KVTile t;
        const ushort* kr = kb + (size_t)(kbase + l15) * DD + hb + l4 * 8;
        t.k0 = *(const bf16x8*)kr;
        t.k1 = *(const bf16x8*)(kr + 32);
        const ushort* vr = vT + (size_t)(hb + l15) * SS + kbase + l4 * 4;
        t.v0 = *(const s16x4*)vr;
        t.v1 = *(const s16x4*)(vr + 16 * SS);
        t.v2 = *(const s16x4*)(vr + 32 * SS);
        t.v3 = *(const s16x4*)(vr + 48 * SS);
        return t;
    };

    auto step = [&](const KVTile& t, bf16x8 Q0, bf16x8 Q1, float& m, float& l,
                    f32x4& O0, f32x4& O1, f32x4& O2, f32x4& O3) {
        f32x4 s = {};
        s = __builtin_amdgcn_mfma_f32_16x16x32_bf16(t.k0, Q0, s, 0, 0, 0);
        s = __builtin_amdgcn_mfma_f32_16x16x32_bf16(t.k1, Q1, s, 0, 0, 0);
        float tm = fmaxf(fmaxf(s[0], s[1]), fmaxf(s[2], s[3]));
        tm = fmaxf(tm, __shfl_xor(tm, 16));
        tm = fmaxf(tm, __shfl_xor(tm, 32));
        if (!__all(tm <= m + 8.0f)) {
            float mn = fmaxf(m, tm);
            float alpha = exp2f(m - mn);
            l *= alpha;
            O0 *= alpha; O1 *= alpha; O2 *= alpha; O3 *= alpha;
            m = mn;
        }
        float p0 = exp2f(s[0] - m), p1 = exp2f(s[1] - m);
        float p2 = exp2f(s[2] - m), p3 = exp2f(s[3] - m);
        float rsum = (p0 + p1) + (p2 + p3);
        rsum += __shfl_xor(rsum, 16);
        rsum += __shfl_xor(rsum, 32);
        l += rsum;
        s16x4 pf;
        pf[0] = (short)f2bf(p0); pf[1] = (short)f2bf(p1);
        pf[2] = (short)f2bf(p2); pf[3] = (short)f2bf(p3);
        O0 = mfma16(t.v0, pf, O0);
        O1 = mfma16(t.v1, pf, O1);
        O2 = mfma16(t.v2, pf, O2);
        O3 = mfma16(t.v3, pf, O3);
    };

    KVTile tA = loadT(bq * 16);        // private: first-half diag tile
    KVTile tB = loadT(NN + bq * 16);   // private: second-half tile bq
    KVTile cur, nxt;
    if (bq > 0) cur = loadT(NN);       // prefetch shared tile 0
    step(tA, qA0, qA1, mA, lA, oA0, oA1, oA2, oA3);
    step(tB, qB0, qB1, mB, lB, oB0, oB1, oB2, oB3);
    for (int t = 0; t < bq; ++t) {
        int tn = (t + 1 < bq) ? t + 1 : bq - 1;
        nxt = loadT(NN + tn * 16);     // prefetch next shared tile
        step(cur, qA0, qA1, mA, lA, oA0, oA1, oA2, oA3);
        step(cur, qB0, qB1, mB, lB, oB0, oB1, oB2, oB3);
        cur = nxt;
    }

    float invA = 1.0f / lA, invB = 1.0f / lB;
    auto st4 = [&](ushort* p, f32x4 v) {
        ushort4 w = {f2bf(v[0]), f2bf(v[1]), f2bf(v[2]), f2bf(v[3])};
        *(ushort4*)p = w;
    };
    ushort* orA = o + (size_t)(q0A + l15) * DD + hb + l4 * 4;
    st4(orA,      oA0 * invA);
    st4(orA + 16, oA1 * invA);
    st4(orA + 32, oA2 * invA);
    st4(orA + 48, oA3 * invA);
    ushort* orB = o + (size_t)(q0B + l15) * DD + hb + l4 * 4;
    st4(orB,      oB0 * invB);
    st4(orB + 16, oB1 * invB);
    st4(orB + 32, oB2 * invB);
    st4(orB + 48, oB3 * invB);
}

extern "C" void kernel_launch(void* const* d_in, const int* in_sizes, int n_in,
                              void* d_out, int out_size, void* d_ws, size_t ws_size,
                              hipStream_t stream) {
    const float* x          = (const float*)d_in[0];
    const float* c          = (const float*)d_in[1];
    const float* cosT       = (const float*)d_in[2];
    const float* sinT       = (const float*)d_in[3];
    const float* norm1_w    = (const float*)d_in[4];
    const float* qkv_w      = (const float*)d_in[5];
    const float* attn_out_w = (const float*)d_in[6];
    const float* norm2_w    = (const float*)d_in[7];
    const float* mlp_w1     = (const float*)d_in[8];
    const float* mlp_b1     = (const float*)d_in[9];
    const float* mlp_w2     = (const float*)d_in[10];
    const float* mlp_b2     = (const float*)d_in[11];
    const float* adaLN_w    = (const float*)d_in[12];
    const float* adaLN_b    = (const float*)d_in[13];
    float* out = (float*)d_out;

    char* p = (char*)d_ws;
    float*  mods = (float*)p;   p += 6 * DD * 4;
    ushort* qkvb = (ushort*)p;  p += (size_t)SS * 3 * DD * 2;   // 12 MB
    ushort* qb   = (ushort*)p;  p += (size_t)SS * DD * 2;       // 4 MB
    ushort* kb   = (ushort*)p;  p += (size_t)SS * DD * 2;
    ushort* vT   = (ushort*)p;  p += (size_t)SS * DD * 2;
    float*  x2   = (float*)p;   p += (size_t)SS * DD * 4;
    ushort* hbuf = (ushort*)p;  p += (size_t)SS * DD * 2;
    ushort* obuf = (ushort*)p;  p += (size_t)SS * DD * 2;
    ushort* wq   = (ushort*)p;  p += (size_t)3 * DD * DD * 2;
    ushort* wo   = (ushort*)p;  p += (size_t)DD * DD * 2;
    ushort* w1   = (ushort*)p;  p += (size_t)4 * DD * DD * 2;
    ushort* w2   = (ushort*)p;  p += (size_t)4 * DD * DD * 2;
    ushort* m1   = qkvb;   // alias: qkvb(12MB)+qb(4MB) dead after k_attn3

    k_cast<<<(3 * DD * DD) / 1024, 256, 0, stream>>>(qkv_w, wq, 3 * DD * DD);
    k_cast<<<(DD * DD) / 1024, 256, 0, stream>>>(attn_out_w, wo, DD * DD);
    k_cast<<<(4 * DD * DD) / 1024, 256, 0, stream>>>(mlp_w1, w1, 4 * DD * DD);
    k_cast<<<(4 * DD * DD) / 1024, 256, 0, stream>>>(mlp_w2, w2, 4 * DD * DD);

    k_adaln<<<6 * DD / 256, 256, 0, stream>>>(c, adaLN_w, adaLN_b, mods);
    k_ln_mod<<<SS, 256, 0, stream>>>(x, norm1_w, mods, 0, 1, hbuf);

    dim3 g1(3 * DD / 128, SS / 128);
    k_gemm_mfma<0, ushort><<<g1, 256, 0, stream>>>(hbuf, wq, nullptr, nullptr, nullptr,
                                                   qkvb, SS, 3 * DD, DD);
    k_rope2<<<512, 256, 0, stream>>>(qkvb, cosT, sinT, qb, kb, vT);
    k_attn3<<<HH * 64, 64, 0, stream>>>(qb, kb, vT, obuf);

    dim3 g2(DD / 128, SS / 128);
    k_gemm_mfma<1, float><<<g2, 256, 0, stream>>>(obuf, wo, nullptr, mods + 2 * DD, x,
                                                  x2, SS, DD, DD);
    k_ln_mod<<<SS, 256, 0, stream>>>(x2, norm2_w, mods, 3, 4, hbuf);

    dim3 g3(4 * DD / 128, SS / 128);
    k_gemm_mfma<2, ushort><<<g3, 256, 0, stream>>>(hbuf, w1, mlp_b1, nullptr, nullptr,
                                                   m1, SS, 4 * DD, DD);
    dim3 g4(DD / 128, SS / 128);
    k_gemm_mfma<3, float><<<g4, 256, 0, stream>>>(m1, w2, mlp_b2, mods + 5 * DD, x2,
                                                  out, SS, DD, 4 * DD);
}

// Round 5
// 181.959 us; speedup vs baseline: 12.1338x; 1.1970x over previous
//
#include <hip/hip_runtime.h>
#include <math.h>

#define SS 2048
#define NN 1024
#define DD 1024
#define HH 16
#define CONDD 128

typedef unsigned short ushort;
typedef unsigned int uint;
typedef __bf16 bf16x8 __attribute__((ext_vector_type(8)));
typedef float f32x4 __attribute__((ext_vector_type(4)));
typedef short s16x4 __attribute__((ext_vector_type(4)));
typedef ushort u16x8 __attribute__((ext_vector_type(8)));

__device__ __forceinline__ float gelu_tanh(float x) {
    float x3 = x * x * x;
    return 0.5f * x * (1.0f + tanhf(0.79788456080286535588f * (x + 0.044715f * x3)));
}

__device__ __forceinline__ ushort f2bf(float x) {
    uint u = __float_as_uint(x);
    u += 0x7fff + ((u >> 16) & 1);
    return (ushort)(u >> 16);
}

__device__ __forceinline__ float bf2f(ushort u) {
    return __uint_as_float(((uint)u) << 16);
}

__device__ __forceinline__ void gload16(const ushort* g, ushort* l) {
    __builtin_amdgcn_global_load_lds(
        (const __attribute__((address_space(1))) void*)g,
        (__attribute__((address_space(3))) void*)l, 16, 0, 0);
}

// 16x16x16 bf16 MFMA (PV step): A,B = 4 bf16 (2 VGPR), C/D = 4 f32
__device__ __forceinline__ f32x4 mfma16(s16x4 a, s16x4 b, f32x4 c) {
#if __has_builtin(__builtin_amdgcn_mfma_f32_16x16x16bf16_1k)
    return __builtin_amdgcn_mfma_f32_16x16x16bf16_1k(a, b, c, 0, 0, 0);
#else
    asm("v_mfma_f32_16x16x16_bf16 %0, %1, %2, %0" : "+v"(c) : "v"(a), "v"(b));
    return c;
#endif
}

// all 4 weight tensors -> one contiguous bf16 region (wq|wo|w1|w2)
__global__ void k_cast4(const float* __restrict__ s0, const float* __restrict__ s1,
                        const float* __restrict__ s2, const float* __restrict__ s3,
                        ushort* __restrict__ dst) {
    size_t gid = ((size_t)blockIdx.x * 256 + threadIdx.x) * 4;
    const float* src;
    size_t off;
    if (gid < (3ull << 20))      { src = s0; off = 0; }
    else if (gid < (4ull << 20)) { src = s1; off = 3ull << 20; }
    else if (gid < (8ull << 20)) { src = s2; off = 4ull << 20; }
    else                         { src = s3; off = 8ull << 20; }
    float4 v = *(const float4*)(src + (gid - off));
    ushort4 o = {f2bf(v.x), f2bf(v.y), f2bf(v.z), f2bf(v.w)};
    *(ushort4*)(dst + gid) = o;
}

// mods[6D] = adaLN_b + adaLN_w @ c
__global__ void k_adaln(const float* __restrict__ c, const float* __restrict__ w,
                        const float* __restrict__ b, float* __restrict__ mods) {
    int o = blockIdx.x * 256 + threadIdx.x;
    float s = b[o];
    const float* wr = w + (size_t)o * CONDD;
    for (int k = 0; k < CONDD; ++k) s += c[k] * wr[k];
    mods[o] = s;
}

// out(bf16)[row] = LN(x[row]) * w * (1 + mods[sc*D+:]) + mods[sh*D+:]
__global__ void k_ln_mod(const float* __restrict__ x, const float* __restrict__ w,
                         const float* __restrict__ mods, int sh_idx, int sc_idx,
                         ushort* __restrict__ out) {
    int row = blockIdx.x;
    int tid = threadIdx.x;
    const float* xr = x + (size_t)row * DD;
    float lx[4];
    float s = 0.f, s2 = 0.f;
    for (int i = 0; i < 4; ++i) {
        float v = xr[tid + i * 256];
        lx[i] = v; s += v; s2 += v * v;
    }
    __shared__ float rs[256], rs2[256];
    rs[tid] = s; rs2[tid] = s2; __syncthreads();
    for (int off = 128; off > 0; off >>= 1) {
        if (tid < off) { rs[tid] += rs[tid + off]; rs2[tid] += rs2[tid + off]; }
        __syncthreads();
    }
    float mu = rs[0] * (1.0f / DD);
    float var = rs2[0] * (1.0f / DD) - mu * mu;
    float rstd = rsqrtf(var + 1e-5f);
    const float* sh = mods + sh_idx * DD;
    const float* sc = mods + sc_idx * DD;
    ushort* orow = out + (size_t)row * DD;
    for (int i = 0; i < 4; ++i) {
        int d = tid + i * 256;
        orow[d] = f2bf((lx[i] - mu) * rstd * w[d] * (1.0f + sc[d]) + sh[d]);
    }
}

// C[M,N] = A[M,K](bf16) @ W[N,K](bf16)^T, fp32 accum, fused epilogue.
// Tile TM x 128, BK=64, 4 waves, mfma_f32_16x16x32_bf16, XOR-swizzled LDS,
// double-buffered 2-phase prefetch (stage t+1 issued before compute t),
// bijective XCD-aware block swizzle (consecutive work-chunks per XCD L2).
// TM=128: waves 2x2 (64x64 quadrant, acc 4x4). TM=64: waves 1x4 (64x32, acc 4x2).
template <int TM, int MODE, typename OT>
__global__ void k_gemm_mfma(const ushort* __restrict__ A, const ushort* __restrict__ W,
                            const float* __restrict__ bias, const float* __restrict__ gate,
                            const float* __restrict__ resid, OT* __restrict__ C,
                            int M, int Nout, int K) {
    constexpr int WC = (TM == 128) ? 2 : 4;   // waves across N
    constexpr int MN = 128 / WC / 16;         // n-frags per wave (4 or 2)
    constexpr int BUFE = (TM + 128) * 64;     // ushorts per buffer
    __shared__ ushort lds[2 * BUFE];

    int tid = threadIdx.x;
    int lane = tid & 63, wave = tid >> 6;
    int wr = (TM == 128) ? (wave >> 1) : 0;
    int wc = (TM == 128) ? (wave & 1) : wave;
    int l15 = lane & 15, l4 = lane >> 4;

    // bijective XCD swizzle (m204): consecutive dispatch ids on one XCD get
    // consecutive work ids -> A-panel reuse in that XCD's private L2.
    int nwg = gridDim.x * gridDim.y;
    int orig = blockIdx.y * gridDim.x + blockIdx.x;
    int q = nwg >> 3, r = nwg & 7;
    int xcd = orig & 7, off = orig >> 3;
    int wgid = (xcd < r ? xcd * (q + 1) : r * (q + 1) + (xcd - r) * q) + off;
    int n0 = (wgid % gridDim.x) * 128;
    int m0 = (wgid / gridDim.x) * TM;

    f32x4 acc[4][MN] = {};

    auto stage = [&](int buf, int k0) {
        ushort* base = lds + buf * BUFE;
#pragma unroll
        for (int i = 0; i < TM / 32; ++i) {            // A: TM*8 chunks
            int cb = (wave * (TM / 32) + i) * 64;
            int ch = cb + lane;
            int row = ch >> 3;
            int kc = (ch & 7) ^ (row & 7);
            gload16(A + (size_t)(m0 + row) * K + k0 + kc * 8, base + cb * 8);
        }
#pragma unroll
        for (int i = 0; i < 4; ++i) {                  // B: 1024 chunks
            int cb = (wave * 4 + i) * 64;
            int ch = cb + lane;
            int row = ch >> 3;
            int kc = (ch & 7) ^ (row & 7);
            gload16(W + (size_t)(n0 + row) * K + k0 + kc * 8, base + TM * 64 + cb * 8);
        }
    };

    auto compute = [&](int buf) {
        const ushort* lA = lds + buf * BUFE;
        const ushort* lB = lA + TM * 64;
#pragma unroll
        for (int sub = 0; sub < 2; ++sub) {
            bf16x8 af[4], bw[MN];
#pragma unroll
            for (int mi = 0; mi < 4; ++mi) {
                int row = wr * 64 + mi * 16 + l15;
                int pos = ((sub << 2) | l4) ^ (row & 7);
                af[mi] = *(const bf16x8*)&lA[row * 64 + pos * 8];
            }
#pragma unroll
            for (int ni = 0; ni < MN; ++ni) {
                int row = wc * (MN * 16) + ni * 16 + l15;
                int pos = ((sub << 2) | l4) ^ (row & 7);
                bw[ni] = *(const bf16x8*)&lB[row * 64 + pos * 8];
            }
#pragma unroll
            for (int mi = 0; mi < 4; ++mi)
#pragma unroll
                for (int ni = 0; ni < MN; ++ni)
                    acc[mi][ni] = __builtin_amdgcn_mfma_f32_16x16x32_bf16(
                        af[mi], bw[ni], acc[mi][ni], 0, 0, 0);
        }
    };

    stage(0, 0);
    __syncthreads();
    int nk = K >> 6;
    for (int t = 0; t < nk; ++t) {
        if (t + 1 < nk) stage((t + 1) & 1, (t + 1) << 6);  // overlaps compute(t)
        compute(t & 1);
        __syncthreads();   // drains vmcnt(0)+lgkmcnt, one barrier per K-step
    }

#pragma unroll
    for (int mi = 0; mi < 4; ++mi) {
#pragma unroll
        for (int r2 = 0; r2 < 4; ++r2) {
            int m = m0 + wr * 64 + mi * 16 + l4 * 4 + r2;
#pragma unroll
            for (int ni = 0; ni < MN; ++ni) {
                int n = n0 + wc * (MN * 16) + ni * 16 + l15;
                float v = acc[mi][ni][r2];
                if (MODE == 1) v = gate[n] * v + resid[(size_t)m * Nout + n];
                if (MODE == 2) v = gelu_tanh(v + bias[n]);
                if (MODE == 3) v = gate[n] * (v + bias[n]) + resid[(size_t)m * Nout + n];
                if (sizeof(OT) == 2) C[(size_t)m * Nout + n] = (OT)f2bf(v);
                else                 C[(size_t)m * Nout + n] = (OT)v;
            }
        }
    }
}

// RoPE on bf16 qkv [s][3][H][64] -> qb[s][D] (scaled by 0.125*log2e), kb[s][D],
// vT[h][d][s] (transposed via LDS). RoPE applied to q, k AND v; pos = s mod N.
__global__ void k_rope2(const ushort* __restrict__ qkvb, const float* __restrict__ cosT,
                        const float* __restrict__ sinT, ushort* __restrict__ qb,
                        ushort* __restrict__ kb, ushort* __restrict__ vT) {
    __shared__ ushort vt[64][65];
    int h = blockIdx.x & 15;
    int st = blockIdx.x >> 4;
    int s0 = st * 64;
    int tid = threadIdx.x;
#pragma unroll
    for (int i = 0; i < 8; ++i) {
        int idx = tid + i * 256;
        int sl = idx >> 5, j = idx & 31;
        int s = s0 + sl;
        int pos = s & (NN - 1);
        float cv = cosT[pos * 32 + j], sv = sinT[pos * 32 + j];
        const ushort* row = qkvb + (size_t)s * 3072 + h * 64;
        float x1 = bf2f(row[j]), x2 = bf2f(row[j + 32]);
        qb[(size_t)s * DD + h * 64 + j]      = f2bf((x1 * cv - x2 * sv) * 0.18033688011f);
        qb[(size_t)s * DD + h * 64 + j + 32] = f2bf((x2 * cv + x1 * sv) * 0.18033688011f);
        x1 = bf2f(row[1024 + j]); x2 = bf2f(row[1024 + j + 32]);
        kb[(size_t)s * DD + h * 64 + j]      = f2bf(x1 * cv - x2 * sv);
        kb[(size_t)s * DD + h * 64 + j + 32] = f2bf(x2 * cv + x1 * sv);
        x1 = bf2f(row[2048 + j]); x2 = bf2f(row[2048 + j + 32]);
        vt[sl][j]      = f2bf(x1 * cv - x2 * sv);
        vt[sl][j + 32] = f2bf(x2 * cv + x1 * sv);
    }
    __syncthreads();
    int drow = tid >> 2, sc = (tid & 3) * 16;
    u16x8 a, b;
#pragma unroll
    for (int i = 0; i < 8; ++i) { a[i] = vt[sc + i][drow]; b[i] = vt[sc + 8 + i][drow]; }
    size_t base = (size_t)(h * 64 + drow) * SS + s0 + sc;
    *(u16x8*)&vT[base] = a;
    *(u16x8*)&vT[base + 8] = b;
}

// MFMA flash attention over the block-diffusion mask (block-granular, BS=16).
// One wave per (head, bq); handles first-half AND second-half q-block bq,
// sharing second-half key tiles 0..bq-1 (loaded once, used for both states).
struct KVTile { bf16x8 k0, k1; s16x4 v0, v1, v2, v3; };

__global__ __launch_bounds__(64) void k_attn3(
        const ushort* __restrict__ qb, const ushort* __restrict__ kb,
        const ushort* __restrict__ vT, ushort* __restrict__ o) {
    int id = blockIdx.x;
    int h = id & 15;
    int bq = 63 - (id >> 4);          // heavy-first
    int lane = threadIdx.x;
    int l15 = lane & 15, l4 = lane >> 4;
    int hb = h * 64;

    const int q0A = bq * 16, q0B = NN + bq * 16;
    bf16x8 qA0 = *(const bf16x8*)&qb[(size_t)(q0A + l15) * DD + hb + l4 * 8];
    bf16x8 qA1 = *(const bf16x8*)&qb[(size_t)(q0A + l15) * DD + hb + 32 + l4 * 8];
    bf16x8 qB0 = *(const bf16x8*)&qb[(size_t)(q0B + l15) * DD + hb + l4 * 8];
    bf16x8 qB1 = *(const bf16x8*)&qb[(size_t)(q0B + l15) * DD + hb + 32 + l4 * 8];

    float mA = -1e30f, lA = 0.f, mB = -1e30f, lB = 0.f;
    f32x4 oA0 = {}, oA1 = {}, oA2 = {}, oA3 = {};
    f32x4 oB0 = {}, oB1 = {}, oB2 = {}, oB3 = {};

    auto loadT = [&](int kbase) {
        KVTile t;
        const ushort* kr = kb + (size_t)(kbase + l15) * DD + hb + l4 * 8;
        t.k0 = *(const bf16x8*)kr;
        t.k1 = *(const bf16x8*)(kr + 32);
        const ushort* vr = vT + (size_t)(hb + l15) * SS + kbase + l4 * 4;
        t.v0 = *(const s16x4*)vr;
        t.v1 = *(const s16x4*)(vr + 16 * SS);
        t.v2 = *(const s16x4*)(vr + 32 * SS);
        t.v3 = *(const s16x4*)(vr + 48 * SS);
        return t;
    };

    auto step = [&](const KVTile& t, bf16x8 Q0, bf16x8 Q1, float& m, float& l,
                    f32x4& O0, f32x4& O1, f32x4& O2, f32x4& O3) {
        f32x4 s = {};
        s = __builtin_amdgcn_mfma_f32_16x16x32_bf16(t.k0, Q0, s, 0, 0, 0);
        s = __builtin_amdgcn_mfma_f32_16x16x32_bf16(t.k1, Q1, s, 0, 0, 0);
        float tm = fmaxf(fmaxf(s[0], s[1]), fmaxf(s[2], s[3]));
        tm = fmaxf(tm, __shfl_xor(tm, 16));
        tm = fmaxf(tm, __shfl_xor(tm, 32));
        if (!__all(tm <= m + 8.0f)) {
            float mn = fmaxf(m, tm);
            float alpha = exp2f(m - mn);
            l *= alpha;
            O0 *= alpha; O1 *= alpha; O2 *= alpha; O3 *= alpha;
            m = mn;
        }
        float p0 = exp2f(s[0] - m), p1 = exp2f(s[1] - m);
        float p2 = exp2f(s[2] - m), p3 = exp2f(s[3] - m);
        float rsum = (p0 + p1) + (p2 + p3);
        rsum += __shfl_xor(rsum, 16);
        rsum += __shfl_xor(rsum, 32);
        l += rsum;
        s16x4 pf;
        pf[0] = (short)f2bf(p0); pf[1] = (short)f2bf(p1);
        pf[2] = (short)f2bf(p2); pf[3] = (short)f2bf(p3);
        O0 = mfma16(t.v0, pf, O0);
        O1 = mfma16(t.v1, pf, O1);
        O2 = mfma16(t.v2, pf, O2);
        O3 = mfma16(t.v3, pf, O3);
    };

    KVTile tA = loadT(bq * 16);        // private: first-half diag tile
    KVTile tB = loadT(NN + bq * 16);   // private: second-half tile bq
    KVTile cur, nxt;
    if (bq > 0) cur = loadT(NN);       // prefetch shared tile 0
    step(tA, qA0, qA1, mA, lA, oA0, oA1, oA2, oA3);
    step(tB, qB0, qB1, mB, lB, oB0, oB1, oB2, oB3);
    for (int t = 0; t < bq; ++t) {
        int tn = (t + 1 < bq) ? t + 1 : bq - 1;
        nxt = loadT(NN + tn * 16);     // prefetch next shared tile
        step(cur, qA0, qA1, mA, lA, oA0, oA1, oA2, oA3);
        step(cur, qB0, qB1, mB, lB, oB0, oB1, oB2, oB3);
        cur = nxt;
    }

    float invA = 1.0f / lA, invB = 1.0f / lB;
    auto st4 = [&](ushort* p, f32x4 v) {
        ushort4 w = {f2bf(v[0]), f2bf(v[1]), f2bf(v[2]), f2bf(v[3])};
        *(ushort4*)p = w;
    };
    ushort* orA = o + (size_t)(q0A + l15) * DD + hb + l4 * 4;
    st4(orA,      oA0 * invA);
    st4(orA + 16, oA1 * invA);
    st4(orA + 32, oA2 * invA);
    st4(orA + 48, oA3 * invA);
    ushort* orB = o + (size_t)(q0B + l15) * DD + hb + l4 * 4;
    st4(orB,      oB0 * invB);
    st4(orB + 16, oB1 * invB);
    st4(orB + 32, oB2 * invB);
    st4(orB + 48, oB3 * invB);
}

extern "C" void kernel_launch(void* const* d_in, const int* in_sizes, int n_in,
                              void* d_out, int out_size, void* d_ws, size_t ws_size,
                              hipStream_t stream) {
    const float* x          = (const float*)d_in[0];
    const float* c          = (const float*)d_in[1];
    const float* cosT       = (const float*)d_in[2];
    const float* sinT       = (const float*)d_in[3];
    const float* norm1_w    = (const float*)d_in[4];
    const float* qkv_w      = (const float*)d_in[5];
    const float* attn_out_w = (const float*)d_in[6];
    const float* norm2_w    = (const float*)d_in[7];
    const float* mlp_w1     = (const float*)d_in[8];
    const float* mlp_b1     = (const float*)d_in[9];
    const float* mlp_w2     = (const float*)d_in[10];
    const float* mlp_b2     = (const float*)d_in[11];
    const float* adaLN_w    = (const float*)d_in[12];
    const float* adaLN_b    = (const float*)d_in[13];
    float* out = (float*)d_out;

    char* p = (char*)d_ws;
    float*  mods = (float*)p;   p += 6 * DD * 4;
    ushort* qkvb = (ushort*)p;  p += (size_t)SS * 3 * DD * 2;   // 12 MB
    ushort* qb   = (ushort*)p;  p += (size_t)SS * DD * 2;       // 4 MB
    ushort* kb   = (ushort*)p;  p += (size_t)SS * DD * 2;
    ushort* vT   = (ushort*)p;  p += (size_t)SS * DD * 2;
    float*  x2   = (float*)p;   p += (size_t)SS * DD * 4;
    ushort* hbuf = (ushort*)p;  p += (size_t)SS * DD * 2;
    ushort* obuf = (ushort*)p;  p += (size_t)SS * DD * 2;
    ushort* wq   = (ushort*)p;  p += (size_t)3 * DD * DD * 2;   // contiguous:
    ushort* wo   = (ushort*)p;  p += (size_t)DD * DD * 2;       //   wq|wo|w1|w2
    ushort* w1   = (ushort*)p;  p += (size_t)4 * DD * DD * 2;
    ushort* w2   = (ushort*)p;  p += (size_t)4 * DD * DD * 2;
    ushort* m1   = qkvb;   // alias: qkvb(12MB)+qb(4MB) dead after k_attn3

    k_cast4<<<(12 << 20) / 1024, 256, 0, stream>>>(qkv_w, attn_out_w, mlp_w1, mlp_w2, wq);

    k_adaln<<<6 * DD / 256, 256, 0, stream>>>(c, adaLN_w, adaLN_b, mods);
    k_ln_mod<<<SS, 256, 0, stream>>>(x, norm1_w, mods, 0, 1, hbuf);

    dim3 g1(3 * DD / 128, SS / 128);   // 24 x 16 = 384 blocks
    k_gemm_mfma<128, 0, ushort><<<g1, 256, 0, stream>>>(hbuf, wq, nullptr, nullptr,
                                                        nullptr, qkvb, SS, 3 * DD, DD);
    k_rope2<<<512, 256, 0, stream>>>(qkvb, cosT, sinT, qb, kb, vT);
    k_attn3<<<HH * 64, 64, 0, stream>>>(qb, kb, vT, obuf);

    dim3 g2(DD / 128, SS / 64);        // 8 x 32 = 256 blocks
    k_gemm_mfma<64, 1, float><<<g2, 256, 0, stream>>>(obuf, wo, nullptr, mods + 2 * DD,
                                                      x, x2, SS, DD, DD);
    k_ln_mod<<<SS, 256, 0, stream>>>(x2, norm2_w, mods, 3, 4, hbuf);

    dim3 g3(4 * DD / 128, SS / 128);   // 32 x 16 = 512 blocks
    k_gemm_mfma<128, 2, ushort><<<g3, 256, 0, stream>>>(hbuf, w1, mlp_b1, nullptr,
                                                        nullptr, m1, SS, 4 * DD, DD);
    dim3 g4(DD / 128, SS / 64);        // 8 x 32 = 256 blocks
    k_gemm_mfma<64, 3, float><<<g4, 256, 0, stream>>>(m1, w2, mlp_b2, mods + 5 * DD,
                                                      x2, out, SS, DD, 4 * DD);
}